// Round 7
// baseline (289.254 us; speedup 1.0000x reference)
//
#include <hip/hip_runtime.h>
#include <hip/hip_bf16.h>

// MultiHeadSelfAttention: B=2, S=2048, D=1024, H=16, Dh=64, RoPE theta=1e4, causal.
// Round 7: (a) attn BQ=128 — 32 q-rows/wave so K/V frags+staging amortize over 2 A-frags,
// uniform per-CU work via complement pairing; (b) qkv/out_proj staging uses packed
// v_cvt_pk_bf16_f32 (__float22bfloat162_rn) instead of scalar f2bf chains.
// ws (u16): Q[b,h,s,d] | K[b,h,s,d] | Vt[b,h,d,s] | AO[b,s,h*d], 4M elems each = 32 MB.

#define D_MODEL 1024
#define NHEADS  16
#define HDIM    64
#define SEQ     2048
#define BATCH   2

typedef unsigned short u16;
typedef __bf16 bf16x8_t __attribute__((ext_vector_type(8)));
typedef float  f32x4_t  __attribute__((ext_vector_type(4)));

__device__ __forceinline__ u16 f2bf(float f) {
    union { __hip_bfloat16 h; u16 u; } cv;
    cv.h = __float2bfloat16(f);
    return cv.u;
}

__device__ __forceinline__ unsigned pk2(float x, float y) {
    union { __hip_bfloat162 h; unsigned u; } cv;
    cv.h = __float22bfloat162_rn(make_float2(x, y));   // v_cvt_pk_bf16_f32
    return cv.u;
}

__device__ __forceinline__ uint4 pack8(float4 a, float4 b) {
    uint4 u;
    u.x = pk2(a.x, a.y);
    u.y = pk2(a.z, a.w);
    u.z = pk2(b.x, b.y);
    u.w = pk2(b.z, b.w);
    return u;
}

__device__ __forceinline__ bf16x8_t frag_ld(const u16* p) {
    union { uint4 u; bf16x8_t v; } t;
    t.u = *(const uint4*)p;
    return t.v;
}

// ---------------------------------------------------------------------------
// QKV projection + RoPE. C = X(4096x1024) * W^T, virtual N=3072 (q|k|v).
// 128x128 tile, BK=64, 4 waves 2x2. Q output pre-scaled by 1/8 (attn fold).
// ---------------------------------------------------------------------------
__global__ __launch_bounds__(256) void qkv_rope_kernel(
    const float* __restrict__ X, const float* __restrict__ Wq,
    const float* __restrict__ Wk, const float* __restrict__ Wv,
    const int* __restrict__ pos,
    u16* __restrict__ Qo, u16* __restrict__ Ko, u16* __restrict__ Vt)
{
    __shared__ __align__(16) u16 smem[2 * 128 * 72];        // 36864 B
    u16 (*As)[72] = (u16(*)[72])smem;                       // As[m][k]
    u16 (*Bs)[72] = (u16(*)[72])(smem + 128 * 72);          // Bs[n][k]

    const int tid = threadIdx.x;
    const int m0 = blockIdx.y * 128;
    const int nv = blockIdx.x * 128;
    const int which = nv >> 10;                 // 0=q,1=k,2=v (block-uniform)
    const int nbase = nv & 1023;
    const float* __restrict__ W = (which == 0) ? Wq : (which == 1) ? Wk : Wv;

    const int w = tid >> 6, L = tid & 63, quad = L >> 4, colL = L & 15;
    const int mw = (w & 1) * 64, nw = (w >> 1) * 64;
    const int srow = tid >> 3, skc = (tid & 7) * 8;

    f32x4_t acc[4][4];
    #pragma unroll
    for (int i = 0; i < 4; ++i)
        #pragma unroll
        for (int j = 0; j < 4; ++j) acc[i][j] = (f32x4_t){0.f, 0.f, 0.f, 0.f};

    for (int k0 = 0; k0 < D_MODEL; k0 += 64) {
        uint4 ar[4], br[4];
        #pragma unroll
        for (int p2 = 0; p2 < 4; ++p2) {
            const int row = srow + 32 * p2;
            const float* xp = X + (size_t)(m0 + row) * D_MODEL + k0 + skc;
            ar[p2] = pack8(*(const float4*)xp, *(const float4*)(xp + 4));
            const float* wp = W + (size_t)(nbase + row) * D_MODEL + k0 + skc;
            br[p2] = pack8(*(const float4*)wp, *(const float4*)(wp + 4));
        }
        __syncthreads();
        #pragma unroll
        for (int p2 = 0; p2 < 4; ++p2) {
            const int row = srow + 32 * p2;
            *(uint4*)&As[row][skc] = ar[p2];
            *(uint4*)&Bs[row][skc] = br[p2];
        }
        __syncthreads();
        #pragma unroll
        for (int kb = 0; kb < 2; ++kb) {
            bf16x8_t af[4], bf[4];
            #pragma unroll
            for (int t = 0; t < 4; ++t) {
                af[t] = frag_ld(&As[mw + t * 16 + colL][kb * 32 + quad * 8]);
                bf[t] = frag_ld(&Bs[nw + t * 16 + colL][kb * 32 + quad * 8]);
            }
            #pragma unroll
            for (int mt = 0; mt < 4; ++mt)
                #pragma unroll
                for (int nt = 0; nt < 4; ++nt)
                    acc[mt][nt] = __builtin_amdgcn_mfma_f32_16x16x32_bf16(
                        af[mt], bf[nt], acc[mt][nt], 0, 0, 0);
        }
    }

    // ---- epilogue: RoPE (regs) -> LDS tile -> coalesced stores ----
    __syncthreads();                            // done with As/Bs
    u16 (*Ts)[132] = (u16(*)[132])smem;         // 128x132 u16 = 33792 B

    const float C0 = 0.14391156831212787f;      // ln(10000)/64
    if (which < 2) {
        const float oscale = (which == 0) ? 0.125f : 1.0f;   // fold 1/sqrt(64) into Q
        float invf[4], sgn[4];
        #pragma unroll
        for (int nt = 0; nt < 4; ++nt) {
            const int n = nbase + nw + nt * 16 + colL;
            const int dd = n & 63;
            invf[nt] = __expf(-(float)(dd & 62) * C0);
            sgn[nt] = (dd & 1) ? 1.0f : -1.0f;
        }
        #pragma unroll
        for (int mt = 0; mt < 4; ++mt) {
            #pragma unroll
            for (int r = 0; r < 4; ++r) {
                const int ml = mw + mt * 16 + quad * 4 + r;
                const int ss = (m0 + ml) & 2047;
                const float p = (float)pos[ss];
                #pragma unroll
                for (int nt = 0; nt < 4; ++nt) {
                    const float v = acc[mt][nt][r];
                    const float partner = __shfl_xor(v, 1);
                    float sn, cs;
                    __sincosf(p * invf[nt], &sn, &cs);   // native, no libcall scratch
                    Ts[ml][nw + nt * 16 + colL] =
                        f2bf((v * cs + sgn[nt] * sn * partner) * oscale);
                }
            }
        }
    } else {
        #pragma unroll
        for (int mt = 0; mt < 4; ++mt)
            #pragma unroll
            for (int nt = 0; nt < 4; ++nt)
                #pragma unroll
                for (int r = 0; r < 4; ++r)
                    Ts[nw + nt * 16 + colL][mw + mt * 16 + quad * 4 + r] = f2bf(acc[mt][nt][r]);
    }
    __syncthreads();

    const int rr0 = tid >> 4;                   // 0..15
    const int cc8 = (tid & 15) * 8;             // 0..120, 8-u16 chunks
    if (which < 2) {
        u16* __restrict__ dst = (which == 0) ? Qo : Ko;
        #pragma unroll
        for (int it = 0; it < 8; ++it) {
            const int ml = rr0 + it * 16;
            const int m = m0 + ml, bb = m >> 11, ss = m & 2047;
            const int n = nbase + cc8, h = n >> 6, d = n & 63;
            *(uint4*)&dst[((size_t)(bb * NHEADS + h) * SEQ + ss) * HDIM + d] =
                *(const uint4*)&Ts[ml][cc8];
        }
    } else {
        const int bb = m0 >> 11, ss0 = (m0 & 2047) + cc8;
        #pragma unroll
        for (int it = 0; it < 8; ++it) {
            const int nl = rr0 + it * 16;
            const int n = nbase + nl, h = n >> 6, d = n & 63;
            *(uint4*)&Vt[((size_t)(bb * NHEADS + h) * HDIM + d) * SEQ + ss0] =
                *(const uint4*)&Ts[nl][cc8];
        }
    }
}

// ---------------------------------------------------------------------------
// Flash attention, causal, MFMA, max-free softmax. Block = (b, h, 128-q rows),
// 4 waves x 32 q-rows (2 A-frags/wave share K/V B-frags). K/V reg-prefetched.
// qb pairing across batch halves keeps per-CU work uniform (2 blocks/CU, LPT).
// ---------------------------------------------------------------------------
__global__ __launch_bounds__(256) void attn_kernel(
    const u16* __restrict__ Q, const u16* __restrict__ K,
    const u16* __restrict__ Vt, u16* __restrict__ AO)
{
    __shared__ __align__(16) u16 Qs[128][72];   // [q][d]
    __shared__ __align__(16) u16 Ks[64][72];    // [key][d]
    __shared__ __align__(16) u16 Vs[64][72];    // [d][key]
    __shared__ __align__(16) u16 Ps[4][32][72]; // per-wave [q_local][key] / AO staging

    const int tid = threadIdx.x;
    const int hh = blockIdx.y, bb = blockIdx.z;
    const int qb = bb ? (int)blockIdx.x : 15 - (int)blockIdx.x;  // complement pairing
    const size_t bh = ((size_t)bb * NHEADS + hh) * (SEQ * HDIM);
    const int q0 = qb * 128;
    const int nkt = 2 * qb + 2;                 // number of 64-key tiles

    const int w = tid >> 6, L = tid & 63, quad = L >> 4, colL = L & 15;
    const int srow = tid >> 2, sc = (tid & 3) * 16;

    {   // stage Q once (pre-scaled by 1/8 in qkv): 128 rows x 64 cols
        const int qrow = tid >> 1, qc = (tid & 1) * 32;
        const u16* qp = Q + bh + (size_t)(q0 + qrow) * HDIM + qc;
        #pragma unroll
        for (int j = 0; j < 4; ++j)
            *(uint4*)&Qs[qrow][qc + 8 * j] = *(const uint4*)(qp + 8 * j);
    }

    const int qw0 = q0 + 32 * w;                // wave's first q row (abs)
    const int qmaxw = qw0 + 31;                 // wave's last q row (abs)

    float lsum[2][4];
    f32x4_t O[2][4];
    #pragma unroll
    for (int f = 0; f < 2; ++f)
        #pragma unroll
        for (int r = 0; r < 4; ++r) {
            lsum[f][r] = 0.f;
            O[f][r] = (f32x4_t){0.f, 0.f, 0.f, 0.f};
        }

    // prefetch tile 0 into registers
    const u16* kp = K + bh + (size_t)srow * HDIM + sc;
    const u16* vp = Vt + bh + (size_t)srow * SEQ + sc;
    uint4 kv0 = *(const uint4*)kp;
    uint4 kv1 = *(const uint4*)(kp + 8);
    uint4 vv0 = *(const uint4*)vp;
    uint4 vv1 = *(const uint4*)(vp + 8);

    for (int kt = 0; kt < nkt; ++kt) {
        const int k0 = kt * 64;
        __syncthreads();                        // prev tile's frag reads done
        *(uint4*)&Ks[srow][sc]     = kv0;
        *(uint4*)&Ks[srow][sc + 8] = kv1;
        *(uint4*)&Vs[srow][sc]     = vv0;
        *(uint4*)&Vs[srow][sc + 8] = vv1;
        if (kt + 1 < nkt) {                     // prefetch next tile
            const int k1 = k0 + 64;
            const u16* kpn = K + bh + (size_t)(k1 + srow) * HDIM + sc;
            kv0 = *(const uint4*)kpn;
            kv1 = *(const uint4*)(kpn + 8);
            const u16* vpn = Vt + bh + (size_t)srow * SEQ + k1 + sc;
            vv0 = *(const uint4*)vpn;
            vv1 = *(const uint4*)(vpn + 8);
        }
        __syncthreads();

        if (k0 > qmaxw) continue;               // wave fully masked (barriers already hit)

        // sub-block pruning: frag f covers q rows qw0+16f .. qw0+16f+15
        const int ntmax0 = min(3, (qw0 + 15 - k0) >> 4);    // may be -1
        const int ntmax1 = min(3, (qmaxw - k0) >> 4);       // >= 0 here

        f32x4_t S[2][4];
        #pragma unroll
        for (int f = 0; f < 2; ++f)
            #pragma unroll
            for (int nt = 0; nt < 4; ++nt) S[f][nt] = (f32x4_t){0.f, 0.f, 0.f, 0.f};

        #pragma unroll
        for (int kb = 0; kb < 2; ++kb) {
            const bf16x8_t aq0 = frag_ld(&Qs[32 * w + colL][kb * 32 + quad * 8]);
            const bf16x8_t aq1 = frag_ld(&Qs[32 * w + 16 + colL][kb * 32 + quad * 8]);
            for (int nt = 0; nt <= ntmax1; ++nt) {
                const bf16x8_t bk = frag_ld(&Ks[nt * 16 + colL][kb * 32 + quad * 8]);
                if (nt <= ntmax0)
                    S[0][nt] = __builtin_amdgcn_mfma_f32_16x16x32_bf16(aq0, bk, S[0][nt], 0, 0, 0);
                S[1][nt] = __builtin_amdgcn_mfma_f32_16x16x32_bf16(aq1, bk, S[1][nt], 0, 0, 0);
            }
        }

        // max-free softmax: p = exp(s); masked/pruned -> 0. Ps rows fully written.
        #pragma unroll
        for (int f = 0; f < 2; ++f) {
            const int ntm = f ? ntmax1 : ntmax0;
            #pragma unroll
            for (int r = 0; r < 4; ++r) {
                const int qa = qw0 + 16 * f + quad * 4 + r;
                #pragma unroll
                for (int nt = 0; nt < 4; ++nt) {
                    float pv = 0.0f;
                    if (nt <= ntm) {
                        const int key = k0 + nt * 16 + colL;
                        pv = (key <= qa) ? __expf(S[f][nt][r]) : 0.0f;
                    }
                    lsum[f][r] += pv;
                    Ps[w][16 * f + quad * 4 + r][nt * 16 + colL] = f2bf(pv);
                }
            }
        }

        asm volatile("s_waitcnt lgkmcnt(0)" ::: "memory");  // wave-local Ps ready

        const int kbmax0 = (qw0 + 15 - k0) >> 5;            // may be -1
        const int kbmax1 = min(1, (qmaxw - k0) >> 5);       // >= 0
        for (int kb = 0; kb <= kbmax1; ++kb) {
            const bf16x8_t ap1 = frag_ld(&Ps[w][16 + colL][kb * 32 + quad * 8]);
            bf16x8_t ap0;
            if (kb <= kbmax0) ap0 = frag_ld(&Ps[w][colL][kb * 32 + quad * 8]);
            #pragma unroll
            for (int dt = 0; dt < 4; ++dt) {
                const bf16x8_t bv = frag_ld(&Vs[dt * 16 + colL][kb * 32 + quad * 8]);
                if (kb <= kbmax0)
                    O[0][dt] = __builtin_amdgcn_mfma_f32_16x16x32_bf16(ap0, bv, O[0][dt], 0, 0, 0);
                O[1][dt] = __builtin_amdgcn_mfma_f32_16x16x32_bf16(ap1, bv, O[1][dt], 0, 0, 0);
            }
        }
    }

    // deferred l reduction: once, over the 16 lanes of each quad-row
    float inv[2][4];
    #pragma unroll
    for (int f = 0; f < 2; ++f)
        #pragma unroll
        for (int r = 0; r < 4; ++r) {
            float s = lsum[f][r];
            #pragma unroll
            for (int off = 1; off < 16; off <<= 1) s += __shfl_xor(s, off);
            inv[f][r] = 1.0f / s;
        }

    // epilogue: O -> per-wave LDS -> coalesced uint4 stores (32 rows/wave)
    #pragma unroll
    for (int f = 0; f < 2; ++f)
        #pragma unroll
        for (int dt = 0; dt < 4; ++dt)
            #pragma unroll
            for (int r = 0; r < 4; ++r)
                Ps[w][16 * f + quad * 4 + r][dt * 16 + colL] = f2bf(O[f][dt][r] * inv[f][r]);
    asm volatile("s_waitcnt lgkmcnt(0)" ::: "memory");
    #pragma unroll
    for (int p = 0; p < 4; ++p) {
        const int rowl = (L >> 3) + 8 * p;      // 0..31
        const int c8 = (L & 7) * 8;             // 0..56
        const int s = qw0 + rowl;
        *(uint4*)&AO[((size_t)bb * SEQ + s) * D_MODEL + hh * HDIM + c8] =
            *(const uint4*)&Ps[w][rowl][c8];
    }
}

// ---------------------------------------------------------------------------
// Output projection: Out(fp32) = AO(bf16, 4096x1024) * Wo^T(fp32->bf16).
// ---------------------------------------------------------------------------
__global__ __launch_bounds__(256) void out_proj_kernel(
    const u16* __restrict__ A, const float* __restrict__ Wo, float* __restrict__ Out)
{
    __shared__ __align__(16) u16 As[128][72];
    __shared__ __align__(16) u16 Bs[128][72];
    const int tid = threadIdx.x;
    const int m0 = blockIdx.y * 128;
    const int n0 = blockIdx.x * 128;

    const int w = tid >> 6, L = tid & 63, quad = L >> 4, colL = L & 15;
    const int mw = (w & 1) * 64, nw = (w >> 1) * 64;
    const int srow = tid >> 3, skc = (tid & 7) * 8;

    f32x4_t acc[4][4];
    #pragma unroll
    for (int i = 0; i < 4; ++i)
        #pragma unroll
        for (int j = 0; j < 4; ++j) acc[i][j] = (f32x4_t){0.f, 0.f, 0.f, 0.f};

    for (int k0 = 0; k0 < D_MODEL; k0 += 64) {
        uint4 ar[4], br[4];
        #pragma unroll
        for (int p2 = 0; p2 < 4; ++p2) {
            const int row = srow + 32 * p2;
            ar[p2] = *(const uint4*)(A + (size_t)(m0 + row) * D_MODEL + k0 + skc);
            const float* wp = Wo + (size_t)(n0 + row) * D_MODEL + k0 + skc;
            br[p2] = pack8(*(const float4*)wp, *(const float4*)(wp + 4));
        }
        __syncthreads();
        #pragma unroll
        for (int p2 = 0; p2 < 4; ++p2) {
            const int row = srow + 32 * p2;
            *(uint4*)&As[row][skc] = ar[p2];
            *(uint4*)&Bs[row][skc] = br[p2];
        }
        __syncthreads();
        #pragma unroll
        for (int kb = 0; kb < 2; ++kb) {
            bf16x8_t af[4], bf[4];
            #pragma unroll
            for (int t = 0; t < 4; ++t) {
                af[t] = frag_ld(&As[mw + t * 16 + colL][kb * 32 + quad * 8]);
                bf[t] = frag_ld(&Bs[nw + t * 16 + colL][kb * 32 + quad * 8]);
            }
            #pragma unroll
            for (int mt = 0; mt < 4; ++mt)
                #pragma unroll
                for (int nt = 0; nt < 4; ++nt)
                    acc[mt][nt] = __builtin_amdgcn_mfma_f32_16x16x32_bf16(
                        af[mt], bf[nt], acc[mt][nt], 0, 0, 0);
        }
    }

    #pragma unroll
    for (int mt = 0; mt < 4; ++mt)
        #pragma unroll
        for (int nt = 0; nt < 4; ++nt)
            #pragma unroll
            for (int r = 0; r < 4; ++r) {
                const int m = m0 + mw + mt * 16 + quad * 4 + r;
                const int n = n0 + nw + nt * 16 + colL;
                Out[(size_t)m * D_MODEL + n] = acc[mt][nt][r];
            }
}

// ---------------------------------------------------------------------------
extern "C" void kernel_launch(void* const* d_in, const int* in_sizes, int n_in,
                              void* d_out, int out_size, void* d_ws, size_t ws_size,
                              hipStream_t stream) {
    const float* x  = (const float*)d_in[0];
    const float* wq = (const float*)d_in[1];
    const float* wk = (const float*)d_in[2];
    const float* wv = (const float*)d_in[3];
    const float* wo = (const float*)d_in[4];
    const int* pos  = (const int*)d_in[5];
    float* out = (float*)d_out;

    const size_t NELEM = (size_t)BATCH * NHEADS * SEQ * HDIM;  // 4,194,304
    u16* Qw  = (u16*)d_ws;
    u16* Kw  = Qw + NELEM;
    u16* Vtw = Kw + NELEM;
    u16* AOw = Vtw + NELEM;

    qkv_rope_kernel<<<dim3(24, 32), 256, 0, stream>>>(x, wq, wk, wv, pos, Qw, Kw, Vtw);
    attn_kernel<<<dim3(SEQ / 128, NHEADS, BATCH), 256, 0, stream>>>(Qw, Kw, Vtw, AOw);
    out_proj_kernel<<<dim3(8, 32), 256, 0, stream>>>(AOw, wo, out);
}